// Round 14
// baseline (431.029 us; speedup 1.0000x reference)
//
#include <hip/hip_runtime.h>
#include <math.h>

#define BB 32
#define NN 4096
#define DD 768
#define HH 384
#define NCH 8   // feat N-chunks per (b, d-block)

typedef _Float16 half8 __attribute__((ext_vector_type(8)));
typedef float f32x4 __attribute__((ext_vector_type(4)));

// ---------------- Kernel 0: pre-split w1 into f16 hi/lo MFMA-B fragments ----------------
__global__ __launch_bounds__(64) void fapf_prep_w(
    const float* __restrict__ w1, short* __restrict__ whf, short* __restrict__ wlf)
{
    const int cf = blockIdx.x;        // 0..23
    const int kg = blockIdx.y;        // 0..23
    const int l  = threadIdx.x;       // 0..63
    const int c  = cf * 16 + (l & 15);
    const int kb = kg * 32 + (l >> 4) * 8;

    short hs[8], ls[8];
#pragma unroll
    for (int i = 0; i < 8; i++) {
        float v = w1[(size_t)(kb + i) * HH + c];
        _Float16 hi = (_Float16)v;
        _Float16 lo = (_Float16)(v - (float)hi);
        hs[i] = *(short*)&hi;
        ls[i] = *(short*)&lo;
    }
    size_t base = ((size_t)(kg * 24 + cf) * 64 + l) * 8;
#pragma unroll
    for (int i = 0; i < 8; i++) { whf[base + i] = hs[i]; wlf[base + i] = ls[i]; }
}

// ---------------- Kernel 1: scores via 3-term f16-split MFMA, BARRIER-FREE ----------------
// ROUND-17: eliminate LDS staging entirely. Per kg, a lane's A-fragment is 8
// CONTIGUOUS floats of x (row t0+(l&15)+fr*16, cols kg*32+(l>>4)*8): load
// direct from global as 2x float4 (the 4 lane-groups tile each row's 128B
// window exactly -- full line utilization) and hi/lo-split in-register. This
// removes SPLITWRITE, both LDS buffers, and ALL 23 in-loop barriers. The
// 2-barrier-per-chunk lockstep was the invariant across every pinned-at-35%
// schedule (R5-R12); with zero barriers the 12 waves/CU run fully async and
// cross-wave MFMA fills each wave's load-stall holes. Cost: x read 4x from
// L1/L2 (waves share lines), ~64 cvt VALU/kg (== old SPLITWRITE cost).
// vmcnt-FIFO audit: each wait only forces loads consumed an iteration ago.
// x depth-1 prefetch: xv(kg+1) issued mid-iteration, consumed after ~36 MFMA.
// TRIPWIRE: WRITE_SIZE == 512KB (no spill); live set ~140 <= 168 (3 w/EU).
__global__ __launch_bounds__(256)
__attribute__((amdgpu_waves_per_eu(3)))
void fapf_scores_mfma(
    const float* __restrict__ x, const short* __restrict__ whf,
    const short* __restrict__ wlf, const float* __restrict__ b1,
    const float* __restrict__ w2, const float* __restrict__ b2,
    float* __restrict__ scores)
{
    __shared__ float part[32][4];

    const int tid = threadIdx.x;
    const int l   = tid & 63;
    const int cw  = tid >> 6;         // wave = col quarter (96 cols)
    const int t0  = blockIdx.x * 32;  // token base

    f32x4 acc[2][6];
#pragma unroll
    for (int fr = 0; fr < 2; fr++)
#pragma unroll
        for (int cf = 0; cf < 6; cf++) acc[fr][cf] = (f32x4){0.f, 0.f, 0.f, 0.f};

    const half8* whp = (const half8*)whf + (size_t)(cw * 6) * 64 + l;
    const half8* wlp = (const half8*)wlf + (size_t)(cw * 6) * 64 + l;

    // per-lane x row pointers (fr=0 / fr=1), col offset (l>>4)*8
    const float* xr0 = x + (size_t)(t0 + (l & 15)) * DD + (l >> 4) * 8;
    const float* xr1 = xr0 + (size_t)16 * DD;

#define LOADB(dst, ptr, kg)                                                  \
    {                                                                        \
        _Pragma("unroll")                                                    \
        for (int cf = 0; cf < 6; cf++)                                       \
            dst[cf] = (ptr)[(size_t)(kg) * 1536 + (size_t)cf * 64];          \
    }

    half8 bA[6], bB[6];
    float4 xv[4];

    // prologue: first b-term + first x fragment in flight
    LOADB(bA, whp, 0);
    xv[0] = *(const float4*)(xr0);
    xv[1] = *(const float4*)(xr0 + 4);
    xv[2] = *(const float4*)(xr1);
    xv[3] = *(const float4*)(xr1 + 4);

    for (int kg = 0; kg < 24; kg++) {
        // issue bl(kg) before converting/consuming anything
        LOADB(bB, wlp, kg);

        // in-register hi/lo split of this kg's A fragments
        half8 ah[2], al[2];
        {
            union { short s[8]; half8 h; } uh0, ul0, uh1, ul1;
            float f0[8] = {xv[0].x, xv[0].y, xv[0].z, xv[0].w,
                           xv[1].x, xv[1].y, xv[1].z, xv[1].w};
            float f1[8] = {xv[2].x, xv[2].y, xv[2].z, xv[2].w,
                           xv[3].x, xv[3].y, xv[3].z, xv[3].w};
#pragma unroll
            for (int i = 0; i < 8; i++) {
                _Float16 h0 = (_Float16)f0[i];
                _Float16 g0 = (_Float16)(f0[i] - (float)h0);
                uh0.s[i] = *(short*)&h0;
                ul0.s[i] = *(short*)&g0;
                _Float16 h1 = (_Float16)f1[i];
                _Float16 g1 = (_Float16)(f1[i] - (float)h1);
                uh1.s[i] = *(short*)&h1;
                ul1.s[i] = *(short*)&g1;
            }
            ah[0] = uh0.h; al[0] = ul0.h;
            ah[1] = uh1.h; al[1] = ul1.h;
        }

        // x depth-1 prefetch: kg+1's fragments (consumed after ~36 MFMA)
        if (kg < 23) {
            const float* p0 = xr0 + (size_t)(kg + 1) * 32;
            const float* p1 = xr1 + (size_t)(kg + 1) * 32;
            xv[0] = *(const float4*)(p0);
            xv[1] = *(const float4*)(p0 + 4);
            xv[2] = *(const float4*)(p1);
            xv[3] = *(const float4*)(p1 + 4);
        }

        __builtin_amdgcn_s_setprio(1);
#pragma unroll
        for (int fr = 0; fr < 2; fr++)
#pragma unroll
            for (int cf = 0; cf < 6; cf++)
                acc[fr][cf] = __builtin_amdgcn_mfma_f32_16x16x32_f16(
                    ah[fr], bA[cf], acc[fr][cf], 0, 0, 0);
#pragma unroll
        for (int fr = 0; fr < 2; fr++)
#pragma unroll
            for (int cf = 0; cf < 6; cf++)
                acc[fr][cf] = __builtin_amdgcn_mfma_f32_16x16x32_f16(
                    al[fr], bA[cf], acc[fr][cf], 0, 0, 0);
        __builtin_amdgcn_s_setprio(0);

        // issue bh(kg+1) before consuming bB=bl(kg)
        if (kg < 23) LOADB(bA, whp, kg + 1);

        __builtin_amdgcn_s_setprio(1);
#pragma unroll
        for (int fr = 0; fr < 2; fr++)
#pragma unroll
            for (int cf = 0; cf < 6; cf++)
                acc[fr][cf] = __builtin_amdgcn_mfma_f32_16x16x32_f16(
                    ah[fr], bB[cf], acc[fr][cf], 0, 0, 0);
        __builtin_amdgcn_s_setprio(0);
    }

    // ---- epilogue: +b1, exact GELU, *w2, partial row-sums ----
    float b1v[6], w2v[6];
#pragma unroll
    for (int cf = 0; cf < 6; cf++) {
        int col = cw * 96 + cf * 16 + (l & 15);
        b1v[cf] = b1[col];
        w2v[cf] = w2[col];
    }
    float p[2][4];
#pragma unroll
    for (int fr = 0; fr < 2; fr++)
#pragma unroll
        for (int j = 0; j < 4; j++) p[fr][j] = 0.f;
#pragma unroll
    for (int fr = 0; fr < 2; fr++)
#pragma unroll
        for (int cf = 0; cf < 6; cf++)
#pragma unroll
            for (int j = 0; j < 4; j++) {
                float hh = acc[fr][cf][j] + b1v[cf];
                float g  = 0.5f * hh * (1.f + erff(hh * 0.70710678118654752f));
                p[fr][j] = fmaf(g, w2v[cf], p[fr][j]);
            }
#pragma unroll
    for (int m = 8; m >= 1; m >>= 1)
#pragma unroll
        for (int fr = 0; fr < 2; fr++)
#pragma unroll
            for (int j = 0; j < 4; j++)
                p[fr][j] += __shfl_xor(p[fr][j], m, 64);

    if ((l & 15) == 0) {
#pragma unroll
        for (int fr = 0; fr < 2; fr++)
#pragma unroll
            for (int j = 0; j < 4; j++) {
                int row = fr * 16 + (l >> 4) * 4 + j;
                part[row][cw] = p[fr][j];
            }
    }
    __syncthreads();
    if (tid < 32) {
        float lg = part[tid][0] + part[tid][1] + part[tid][2] + part[tid][3] + b2[0];
        scores[t0 + tid] = 1.f / (1.f + expf(-lg));
    }
#undef LOADB
}

// ---------------- Kernel 2: radix-select threshold + fused mask/weights + compaction ----------------
// R13-proven: 4-pass 8-bit radix-select on the float bit pattern (positive
// floats: uint order == float order); 12 barriers vs bitonic's 78; thr is
// bit-exact the kc-th largest element.
__global__ __launch_bounds__(1024) void fapf_select_kernel(
    const float* __restrict__ scores, const int* __restrict__ pct_p,
    float* __restrict__ weights, float* __restrict__ mask,
    float* __restrict__ feat, int* __restrict__ kidx,
    float* __restrict__ kw, int* __restrict__ kcnt)
{
    __shared__ float s[NN];
    __shared__ unsigned int hist[256];
    __shared__ unsigned int sh_bin, sh_above;
    __shared__ float wsum[16];
    __shared__ int scnt;
    const int b = blockIdx.x, tid = threadIdx.x;

    if (tid == 0) scnt = 0;
    for (int i = tid; i < DD; i += 1024) feat[b * DD + i] = 0.f;
    for (int i = tid; i < NN; i += 1024) s[i] = scores[b * NN + i];

    int pct = pct_p[0];
    long long kcl = (long long)NN * pct / 100;
    int kc = (int)kcl;
    if (kc < 1) kc = 1;
    if (kc > NN) kc = NN;

    __syncthreads();

    unsigned int prefix = 0;
    unsigned int kk = (unsigned int)kc;
#pragma unroll
    for (int pass = 0; pass < 4; pass++) {
        const int shift = 24 - pass * 8;
        if (tid < 256) hist[tid] = 0;
        __syncthreads();
        const unsigned int maskAbove =
            (pass == 0) ? 0u : (0xFFFFFFFFu << (shift + 8));
        for (int i = tid; i < NN; i += 1024) {
            unsigned int u = __float_as_uint(s[i]);
            if ((u & maskAbove) == prefix)
                atomicAdd(&hist[(u >> shift) & 0xFFu], 1u);
        }
        __syncthreads();
        if (tid < 64) {
            const int ln = tid;
            unsigned int h0 = hist[4 * ln + 0], h1 = hist[4 * ln + 1];
            unsigned int h2 = hist[4 * ln + 2], h3 = hist[4 * ln + 3];
            unsigned int lsum = h0 + h1 + h2 + h3;
            unsigned int incl = lsum;      // inclusive suffix sum over lanes
#pragma unroll
            for (int off = 1; off < 64; off <<= 1) {
                unsigned int t = __shfl_down(incl, off, 64);
                if (ln + off < 64) incl += t;
            }
            unsigned int above_lanes = incl - lsum;   // lanes > ln
            unsigned int c3 = above_lanes + h3;
            unsigned int c2 = c3 + h2;
            unsigned int c1 = c2 + h1;
            unsigned int c0 = c1 + h0;
            if (c3 >= kk && above_lanes < kk) { sh_bin = 4u * ln + 3u; sh_above = above_lanes; }
            if (c2 >= kk && c3 < kk)          { sh_bin = 4u * ln + 2u; sh_above = c3; }
            if (c1 >= kk && c2 < kk)          { sh_bin = 4u * ln + 1u; sh_above = c2; }
            if (c0 >= kk && c1 < kk)          { sh_bin = 4u * ln + 0u; sh_above = c1; }
        }
        __syncthreads();
        kk -= sh_above;
        prefix |= (sh_bin << shift);
    }
    const float thr = __uint_as_float(prefix);

    float local = 0.f;
    for (int i = tid; i < NN; i += 1024) {
        float v = s[i];
        if (v >= thr) local += v;
    }
#pragma unroll
    for (int off = 32; off >= 1; off >>= 1) local += __shfl_down(local, off, 64);
    if ((tid & 63) == 0) wsum[tid >> 6] = local;
    __syncthreads();
    if (tid < 64) {
        float t = (tid < 16) ? wsum[tid] : 0.f;
#pragma unroll
        for (int off = 8; off >= 1; off >>= 1) t += __shfl_down(t, off, 64);
        if (tid == 0) wsum[0] = t;
    }
    __syncthreads();
    const float inv = 1.f / (wsum[0] + 1e-12f);

    const int lane = tid & 63;
    for (int i = tid; i < NN; i += 1024) {
        float v = s[i];
        bool keep = (v >= thr);
        float m = keep ? 1.f : 0.f;
        weights[b * NN + i] = v * m * inv;
        mask[b * NN + i]    = m;
        if (kidx) {
            unsigned long long bal = __ballot(keep);
            int base = 0;
            if (lane == 0) base = atomicAdd(&scnt, __popcll(bal));
            base = __shfl(base, 0, 64);
            if (keep) {
                int off = __popcll(bal & ((1ULL << lane) - 1ULL));
                kidx[b * NN + base + off] = i;
                kw[b * NN + base + off]   = v * inv;
            }
        }
    }
    if (kidx) {
        __syncthreads();
        if (tid == 0) kcnt[b] = scnt;
    }
}

// ---------------- Kernel 3a: filtered_feat from compact list (float4 gather) ----------------
__global__ __launch_bounds__(256) void fapf_feat_compact(
    const float* __restrict__ x, const int* __restrict__ kidx,
    const float* __restrict__ kw, const int* __restrict__ kcnt,
    float* __restrict__ feat)
{
    const int b  = blockIdx.y;
    const int d0 = blockIdx.x * 256;
    const int ch = blockIdx.z;
    const int dl = threadIdx.x & 63;
    const int ng = threadIdx.x >> 6;   // 0..3 (wave id)

    const int cnt = kcnt[b];
    int per = (cnt + NCH - 1) / NCH;
    int j0 = ch * per; if (j0 > cnt) j0 = cnt;
    int j1 = j0 + per; if (j1 > cnt) j1 = cnt;
    int len = j1 - j0;
    int per_w = (len + 3) >> 2;
    int s = j0 + ng * per_w;
    int e = s + per_w; if (e > j1) e = j1;

    const float* xb  = x + (size_t)b * NN * DD + d0 + dl * 4;
    const int*   ib  = kidx + b * NN;
    const float* wbp = kw + b * NN;

    float4 a[8];
#pragma unroll
    for (int u = 0; u < 8; u++) a[u] = (float4){0.f, 0.f, 0.f, 0.f};

    int j = s;
    for (; j + 8 <= e; j += 8) {
        int   idx[8];
        float ww[8];
#pragma unroll
        for (int u = 0; u < 8; u++) { idx[u] = ib[j + u]; ww[u] = wbp[j + u]; }
        float4 v[8];
#pragma unroll
        for (int u = 0; u < 8; u++)
            v[u] = *(const float4*)&xb[(size_t)idx[u] * DD];
#pragma unroll
        for (int u = 0; u < 8; u++) {
            a[u].x = fmaf(ww[u], v[u].x, a[u].x);
            a[u].y = fmaf(ww[u], v[u].y, a[u].y);
            a[u].z = fmaf(ww[u], v[u].z, a[u].z);
            a[u].w = fmaf(ww[u], v[u].w, a[u].w);
        }
    }
    for (; j < e; j++) {
        float w = wbp[j];
        float4 v = *(const float4*)&xb[(size_t)ib[j] * DD];
        a[0].x = fmaf(w, v.x, a[0].x);
        a[0].y = fmaf(w, v.y, a[0].y);
        a[0].z = fmaf(w, v.z, a[0].z);
        a[0].w = fmaf(w, v.w, a[0].w);
    }

    float4 acc;
    acc.x = ((a[0].x + a[1].x) + (a[2].x + a[3].x)) + ((a[4].x + a[5].x) + (a[6].x + a[7].x));
    acc.y = ((a[0].y + a[1].y) + (a[2].y + a[3].y)) + ((a[4].y + a[5].y) + (a[6].y + a[7].y));
    acc.z = ((a[0].z + a[1].z) + (a[2].z + a[3].z)) + ((a[4].z + a[5].z) + (a[6].z + a[7].z));
    acc.w = ((a[0].w + a[1].w) + (a[2].w + a[3].w)) + ((a[4].w + a[5].w) + (a[6].w + a[7].w));

    __shared__ float4 red[4][64];
    red[ng][dl] = acc;
    __syncthreads();
    if (threadIdx.x < 64) {
        float4 r0 = red[0][dl], r1 = red[1][dl], r2 = red[2][dl], r3 = red[3][dl];
        float* fp = &feat[b * DD + d0 + dl * 4];
        atomicAdd(&fp[0], (r0.x + r1.x) + (r2.x + r3.x));
        atomicAdd(&fp[1], (r0.y + r1.y) + (r2.y + r3.y));
        atomicAdd(&fp[2], (r0.z + r1.z) + (r2.z + r3.z));
        atomicAdd(&fp[3], (r0.w + r1.w) + (r2.w + r3.w));
    }
}

// ---------------- Kernel 3b: dense fallback ----------------
__global__ __launch_bounds__(256) void fapf_feat_dense(
    const float* __restrict__ x, const float* __restrict__ weights,
    float* __restrict__ feat)
{
    const int b  = blockIdx.y;
    const int d0 = blockIdx.x * 64;
    const int dl = threadIdx.x & 63;
    const int ng = threadIdx.x >> 6;   // 0..3

    const float* xb = x + (size_t)b * NN * DD;
    const float* wb = weights + b * NN;

    float a0 = 0.f, a1 = 0.f, a2 = 0.f, a3 = 0.f;
    for (int n = ng; n < NN; n += 16) {
        float w0 = wb[n], w1v = wb[n + 4], w2v = wb[n + 8], w3 = wb[n + 12];
        float v0 = xb[(size_t)(n)      * DD + d0 + dl];
        float v1 = xb[(size_t)(n + 4)  * DD + d0 + dl];
        float v2 = xb[(size_t)(n + 8)  * DD + d0 + dl];
        float v3 = xb[(size_t)(n + 12) * DD + d0 + dl];
        a0 = fmaf(w0, v0, a0);
        a1 = fmaf(w1v, v1, a1);
        a2 = fmaf(w2v, v2, a2);
        a3 = fmaf(w3, v3, a3);
    }
    float acc = (a0 + a1) + (a2 + a3);

    __shared__ float red[4][64];
    red[ng][dl] = acc;
    __syncthreads();
    if (threadIdx.x < 64) {
        feat[b * DD + d0 + dl] =
            (red[0][dl] + red[1][dl]) + (red[2][dl] + red[3][dl]);
    }
}

extern "C" void kernel_launch(void* const* d_in, const int* in_sizes, int n_in,
                              void* d_out, int out_size, void* d_ws, size_t ws_size,
                              hipStream_t stream) {
    const float* x   = (const float*)d_in[0];
    const float* w1  = (const float*)d_in[1];
    const float* b1  = (const float*)d_in[2];
    const float* w2  = (const float*)d_in[3];
    const float* b2  = (const float*)d_in[4];
    const int*   pct = (const int*)d_in[5];

    float* out = (float*)d_out;
    float* feat    = out;                         // [32,768]
    float* weights = out + BB * DD;               // [32,4096]
    float* scores  = weights + BB * NN;           // [32,4096]
    float* mask    = scores + BB * NN;            // [32,4096]

    // d_ws layout: whf (576KB) | wlf (576KB) | kidx (512KB) | kw (512KB) | kcnt (128B)
    short* whf  = (short*)d_ws;
    short* wlf  = whf + 24 * 24 * 64 * 8;
    int*   kidx = (int*)(wlf + 24 * 24 * 64 * 8);
    float* kw   = (float*)(kidx + BB * NN);
    int*   kcnt = (int*)(kw + BB * NN);

    const size_t needed = 2 * (size_t)(24 * 24 * 64 * 8) * sizeof(short)
                        + (size_t)BB * NN * (sizeof(int) + sizeof(float))
                        + BB * sizeof(int);
    const bool compact = ws_size >= needed;

    fapf_prep_w<<<dim3(24, 24), dim3(64), 0, stream>>>(w1, whf, wlf);
    fapf_scores_mfma<<<dim3(BB * NN / 32), dim3(256), 0, stream>>>(
        x, whf, wlf, b1, w2, b2, scores);
    fapf_select_kernel<<<dim3(BB), dim3(1024), 0, stream>>>(
        scores, pct, weights, mask, feat,
        compact ? kidx : (int*)nullptr, kw, kcnt);
    if (compact) {
        fapf_feat_compact<<<dim3(DD / 256, BB, NCH), dim3(256), 0, stream>>>(
            x, kidx, kw, kcnt, feat);
    } else {
        fapf_feat_dense<<<dim3(DD / 64, BB), dim3(256), 0, stream>>>(
            x, weights, feat);
    }
}

// Round 15
// 304.620 us; speedup vs baseline: 1.4150x; 1.4150x over previous
//
#include <hip/hip_runtime.h>
#include <math.h>

#define BB 32
#define NN 4096
#define DD 768
#define HH 384
#define NCH 8   // feat N-chunks per (b, d-block)

typedef _Float16 half8 __attribute__((ext_vector_type(8)));
typedef float f32x4 __attribute__((ext_vector_type(4)));

// ---------------- Kernel 0: pre-split w1 into f16 hi/lo MFMA-B fragments ----------------
__global__ __launch_bounds__(64) void fapf_prep_w(
    const float* __restrict__ w1, short* __restrict__ whf, short* __restrict__ wlf)
{
    const int cf = blockIdx.x;        // 0..23
    const int kg = blockIdx.y;        // 0..23
    const int l  = threadIdx.x;       // 0..63
    const int c  = cf * 16 + (l & 15);
    const int kb = kg * 32 + (l >> 4) * 8;

    short hs[8], ls[8];
#pragma unroll
    for (int i = 0; i < 8; i++) {
        float v = w1[(size_t)(kb + i) * HH + c];
        _Float16 hi = (_Float16)v;
        _Float16 lo = (_Float16)(v - (float)hi);
        hs[i] = *(short*)&hi;
        ls[i] = *(short*)&lo;
    }
    size_t base = ((size_t)(kg * 24 + cf) * 64 + l) * 8;
#pragma unroll
    for (int i = 0; i < 8; i++) { whf[base + i] = hs[i]; wlf[base + i] = ls[i]; }
}

// ---------------- Kernel 1: scores via 3-term f16-split MFMA ----------------
// FINAL (R13 revert). R14's barrier-free direct-global A-load regressed to
// 443us: per-lane fragment loads are 16-way row-gathers (3KB lane stride) --
// LDS staging exists to fix exactly that transpose. Seven schedule variants
// (b-depth 0/1/2, half-b, in-body x-issue, LDS-only barrier, occupancy 2-4w,
// no-LDS) bracket this structure at 285-306us = the 2-barrier-loop
// structural ceiling (~41% of the f16 MFMA floor; cf. guide m97 ~36-38%).
// Next level requires the 8-phase co-designed template (ground-up rewrite).
__global__ __launch_bounds__(256)
__attribute__((amdgpu_waves_per_eu(3)))
void fapf_scores_mfma(
    const float* __restrict__ x, const short* __restrict__ whf,
    const short* __restrict__ wlf, const float* __restrict__ b1,
    const float* __restrict__ w2, const float* __restrict__ b2,
    float* __restrict__ scores)
{
    __shared__ __align__(16) short xh[2][32 * 64];
    __shared__ __align__(16) short xl[2][32 * 64];
    __shared__ float part[32][4];

    const int tid = threadIdx.x;
    const int l   = tid & 63;
    const int cw  = tid >> 6;         // wave = col quarter (96 cols)
    const int t0  = blockIdx.x * 32;  // token base

    f32x4 acc[2][6];
#pragma unroll
    for (int fr = 0; fr < 2; fr++)
#pragma unroll
        for (int cf = 0; cf < 6; cf++) acc[fr][cf] = (f32x4){0.f, 0.f, 0.f, 0.f};

    const half8* whp = (const half8*)whf + (size_t)(cw * 6) * 64 + l;
    const half8* wlp = (const half8*)wlf + (size_t)(cw * 6) * 64 + l;

    float4 xv[2];

#define LOADX(ch)                                                            \
    {                                                                        \
        _Pragma("unroll")                                                    \
        for (int it = 0; it < 2; it++) {                                     \
            int id = it * 256 + tid;                                         \
            xv[it] = *(const float4*)&x[(size_t)(t0 + (id >> 4)) * DD        \
                                        + (ch) * 64 + (id & 15) * 4];        \
        }                                                                    \
    }

#define SPLITWRITE(buf)                                                      \
    {                                                                        \
        _Pragma("unroll")                                                    \
        for (int it = 0; it < 2; it++) {                                     \
            int id = it * 256 + tid;                                         \
            int row = id >> 4, seg = id & 15;                                \
            union { short s[4]; uint2 u; } ph, pl;                           \
            float vv[4] = {xv[it].x, xv[it].y, xv[it].z, xv[it].w};          \
            _Pragma("unroll")                                                \
            for (int i = 0; i < 4; i++) {                                    \
                _Float16 hi = (_Float16)vv[i];                               \
                _Float16 lo = (_Float16)(vv[i] - (float)hi);                 \
                ph.s[i] = *(short*)&hi;                                      \
                pl.s[i] = *(short*)&lo;                                      \
            }                                                                \
            int idx = (row * 64 + seg * 4) ^ ((row & 7) << 3);               \
            *(uint2*)&xh[buf][idx] = ph.u;                                   \
            *(uint2*)&xl[buf][idx] = pl.u;                                   \
        }                                                                    \
    }

#define LOADB(dst, ptr, kg)                                                  \
    {                                                                        \
        _Pragma("unroll")                                                    \
        for (int cf = 0; cf < 6; cf++)                                       \
            dst[cf] = (ptr)[(size_t)(kg) * 1536 + (size_t)cf * 64];          \
    }

    LOADX(0);
    SPLITWRITE(0);
    half8 bA[6], bB[6];
    LOADB(bA, whp, 0);                 // bh(kg=0)
    __syncthreads();

    for (int c = 0; c < 12; c++) {
        const int cur = c & 1;

#pragma unroll
        for (int ks = 0; ks < 2; ks++) {
            const int kg = c * 2 + ks;

            half8 ah[2], al[2];
#pragma unroll
            for (int fr = 0; fr < 2; fr++) {
                int row = fr * 16 + (l & 15);
                int idx = (row * 64 + ks * 32 + (l >> 4) * 8) ^ ((row & 7) << 3);
                ah[fr] = *(const half8*)&xh[cur][idx];
                al[fr] = *(const half8*)&xl[cur][idx];
            }

            LOADB(bB, wlp, kg);

            __builtin_amdgcn_s_setprio(1);
#pragma unroll
            for (int fr = 0; fr < 2; fr++)
#pragma unroll
                for (int cf = 0; cf < 6; cf++)
                    acc[fr][cf] = __builtin_amdgcn_mfma_f32_16x16x32_f16(
                        ah[fr], bA[cf], acc[fr][cf], 0, 0, 0);
#pragma unroll
            for (int fr = 0; fr < 2; fr++)
#pragma unroll
                for (int cf = 0; cf < 6; cf++)
                    acc[fr][cf] = __builtin_amdgcn_mfma_f32_16x16x32_f16(
                        al[fr], bA[cf], acc[fr][cf], 0, 0, 0);
            __builtin_amdgcn_s_setprio(0);

            if (kg < 23) LOADB(bA, whp, kg + 1);
            if (ks == 0 && c < 11) LOADX(c + 1);

            __builtin_amdgcn_s_setprio(1);
#pragma unroll
            for (int fr = 0; fr < 2; fr++)
#pragma unroll
                for (int cf = 0; cf < 6; cf++)
                    acc[fr][cf] = __builtin_amdgcn_mfma_f32_16x16x32_f16(
                        ah[fr], bB[cf], acc[fr][cf], 0, 0, 0);
            __builtin_amdgcn_s_setprio(0);
        }

        if (c < 11) {
            SPLITWRITE(cur ^ 1);
            __syncthreads();
        }
    }

    // ---- epilogue: +b1, exact GELU, *w2, partial row-sums ----
    float b1v[6], w2v[6];
#pragma unroll
    for (int cf = 0; cf < 6; cf++) {
        int col = cw * 96 + cf * 16 + (l & 15);
        b1v[cf] = b1[col];
        w2v[cf] = w2[col];
    }
    float p[2][4];
#pragma unroll
    for (int fr = 0; fr < 2; fr++)
#pragma unroll
        for (int j = 0; j < 4; j++) p[fr][j] = 0.f;
#pragma unroll
    for (int fr = 0; fr < 2; fr++)
#pragma unroll
        for (int cf = 0; cf < 6; cf++)
#pragma unroll
            for (int j = 0; j < 4; j++) {
                float hh = acc[fr][cf][j] + b1v[cf];
                float g  = 0.5f * hh * (1.f + erff(hh * 0.70710678118654752f));
                p[fr][j] = fmaf(g, w2v[cf], p[fr][j]);
            }
#pragma unroll
    for (int m = 8; m >= 1; m >>= 1)
#pragma unroll
        for (int fr = 0; fr < 2; fr++)
#pragma unroll
            for (int j = 0; j < 4; j++)
                p[fr][j] += __shfl_xor(p[fr][j], m, 64);

    if ((l & 15) == 0) {
#pragma unroll
        for (int fr = 0; fr < 2; fr++)
#pragma unroll
            for (int j = 0; j < 4; j++) {
                int row = fr * 16 + (l >> 4) * 4 + j;
                part[row][cw] = p[fr][j];
            }
    }
    __syncthreads();
    if (tid < 32) {
        float lg = part[tid][0] + part[tid][1] + part[tid][2] + part[tid][3] + b2[0];
        scores[t0 + tid] = 1.f / (1.f + expf(-lg));
    }
#undef LOADX
#undef SPLITWRITE
#undef LOADB
}

// ---------------- Kernel 2: radix-select threshold + fused mask/weights + compaction ----------------
// R13-proven: 4-pass 8-bit radix-select on the float bit pattern (positive
// floats: uint order == float order); 12 barriers vs bitonic's 78; thr is
// bit-exact the kc-th largest element.
__global__ __launch_bounds__(1024) void fapf_select_kernel(
    const float* __restrict__ scores, const int* __restrict__ pct_p,
    float* __restrict__ weights, float* __restrict__ mask,
    float* __restrict__ feat, int* __restrict__ kidx,
    float* __restrict__ kw, int* __restrict__ kcnt)
{
    __shared__ float s[NN];
    __shared__ unsigned int hist[256];
    __shared__ unsigned int sh_bin, sh_above;
    __shared__ float wsum[16];
    __shared__ int scnt;
    const int b = blockIdx.x, tid = threadIdx.x;

    if (tid == 0) scnt = 0;
    for (int i = tid; i < DD; i += 1024) feat[b * DD + i] = 0.f;
    for (int i = tid; i < NN; i += 1024) s[i] = scores[b * NN + i];

    int pct = pct_p[0];
    long long kcl = (long long)NN * pct / 100;
    int kc = (int)kcl;
    if (kc < 1) kc = 1;
    if (kc > NN) kc = NN;

    __syncthreads();

    unsigned int prefix = 0;
    unsigned int kk = (unsigned int)kc;
#pragma unroll
    for (int pass = 0; pass < 4; pass++) {
        const int shift = 24 - pass * 8;
        if (tid < 256) hist[tid] = 0;
        __syncthreads();
        const unsigned int maskAbove =
            (pass == 0) ? 0u : (0xFFFFFFFFu << (shift + 8));
        for (int i = tid; i < NN; i += 1024) {
            unsigned int u = __float_as_uint(s[i]);
            if ((u & maskAbove) == prefix)
                atomicAdd(&hist[(u >> shift) & 0xFFu], 1u);
        }
        __syncthreads();
        if (tid < 64) {
            const int ln = tid;
            unsigned int h0 = hist[4 * ln + 0], h1 = hist[4 * ln + 1];
            unsigned int h2 = hist[4 * ln + 2], h3 = hist[4 * ln + 3];
            unsigned int lsum = h0 + h1 + h2 + h3;
            unsigned int incl = lsum;      // inclusive suffix sum over lanes
#pragma unroll
            for (int off = 1; off < 64; off <<= 1) {
                unsigned int t = __shfl_down(incl, off, 64);
                if (ln + off < 64) incl += t;
            }
            unsigned int above_lanes = incl - lsum;   // lanes > ln
            unsigned int c3 = above_lanes + h3;
            unsigned int c2 = c3 + h2;
            unsigned int c1 = c2 + h1;
            unsigned int c0 = c1 + h0;
            if (c3 >= kk && above_lanes < kk) { sh_bin = 4u * ln + 3u; sh_above = above_lanes; }
            if (c2 >= kk && c3 < kk)          { sh_bin = 4u * ln + 2u; sh_above = c3; }
            if (c1 >= kk && c2 < kk)          { sh_bin = 4u * ln + 1u; sh_above = c2; }
            if (c0 >= kk && c1 < kk)          { sh_bin = 4u * ln + 0u; sh_above = c1; }
        }
        __syncthreads();
        kk -= sh_above;
        prefix |= (sh_bin << shift);
    }
    const float thr = __uint_as_float(prefix);

    float local = 0.f;
    for (int i = tid; i < NN; i += 1024) {
        float v = s[i];
        if (v >= thr) local += v;
    }
#pragma unroll
    for (int off = 32; off >= 1; off >>= 1) local += __shfl_down(local, off, 64);
    if ((tid & 63) == 0) wsum[tid >> 6] = local;
    __syncthreads();
    if (tid < 64) {
        float t = (tid < 16) ? wsum[tid] : 0.f;
#pragma unroll
        for (int off = 8; off >= 1; off >>= 1) t += __shfl_down(t, off, 64);
        if (tid == 0) wsum[0] = t;
    }
    __syncthreads();
    const float inv = 1.f / (wsum[0] + 1e-12f);

    const int lane = tid & 63;
    for (int i = tid; i < NN; i += 1024) {
        float v = s[i];
        bool keep = (v >= thr);
        float m = keep ? 1.f : 0.f;
        weights[b * NN + i] = v * m * inv;
        mask[b * NN + i]    = m;
        if (kidx) {
            unsigned long long bal = __ballot(keep);
            int base = 0;
            if (lane == 0) base = atomicAdd(&scnt, __popcll(bal));
            base = __shfl(base, 0, 64);
            if (keep) {
                int off = __popcll(bal & ((1ULL << lane) - 1ULL));
                kidx[b * NN + base + off] = i;
                kw[b * NN + base + off]   = v * inv;
            }
        }
    }
    if (kidx) {
        __syncthreads();
        if (tid == 0) kcnt[b] = scnt;
    }
}

// ---------------- Kernel 3a: filtered_feat from compact list (float4 gather) ----------------
__global__ __launch_bounds__(256) void fapf_feat_compact(
    const float* __restrict__ x, const int* __restrict__ kidx,
    const float* __restrict__ kw, const int* __restrict__ kcnt,
    float* __restrict__ feat)
{
    const int b  = blockIdx.y;
    const int d0 = blockIdx.x * 256;
    const int ch = blockIdx.z;
    const int dl = threadIdx.x & 63;
    const int ng = threadIdx.x >> 6;   // 0..3 (wave id)

    const int cnt = kcnt[b];
    int per = (cnt + NCH - 1) / NCH;
    int j0 = ch * per; if (j0 > cnt) j0 = cnt;
    int j1 = j0 + per; if (j1 > cnt) j1 = cnt;
    int len = j1 - j0;
    int per_w = (len + 3) >> 2;
    int s = j0 + ng * per_w;
    int e = s + per_w; if (e > j1) e = j1;

    const float* xb  = x + (size_t)b * NN * DD + d0 + dl * 4;
    const int*   ib  = kidx + b * NN;
    const float* wbp = kw + b * NN;

    float4 a[8];
#pragma unroll
    for (int u = 0; u < 8; u++) a[u] = (float4){0.f, 0.f, 0.f, 0.f};

    int j = s;
    for (; j + 8 <= e; j += 8) {
        int   idx[8];
        float ww[8];
#pragma unroll
        for (int u = 0; u < 8; u++) { idx[u] = ib[j + u]; ww[u] = wbp[j + u]; }
        float4 v[8];
#pragma unroll
        for (int u = 0; u < 8; u++)
            v[u] = *(const float4*)&xb[(size_t)idx[u] * DD];
#pragma unroll
        for (int u = 0; u < 8; u++) {
            a[u].x = fmaf(ww[u], v[u].x, a[u].x);
            a[u].y = fmaf(ww[u], v[u].y, a[u].y);
            a[u].z = fmaf(ww[u], v[u].z, a[u].z);
            a[u].w = fmaf(ww[u], v[u].w, a[u].w);
        }
    }
    for (; j < e; j++) {
        float w = wbp[j];
        float4 v = *(const float4*)&xb[(size_t)ib[j] * DD];
        a[0].x = fmaf(w, v.x, a[0].x);
        a[0].y = fmaf(w, v.y, a[0].y);
        a[0].z = fmaf(w, v.z, a[0].z);
        a[0].w = fmaf(w, v.w, a[0].w);
    }

    float4 acc;
    acc.x = ((a[0].x + a[1].x) + (a[2].x + a[3].x)) + ((a[4].x + a[5].x) + (a[6].x + a[7].x));
    acc.y = ((a[0].y + a[1].y) + (a[2].y + a[3].y)) + ((a[4].y + a[5].y) + (a[6].y + a[7].y));
    acc.z = ((a[0].z + a[1].z) + (a[2].z + a[3].z)) + ((a[4].z + a[5].z) + (a[6].z + a[7].z));
    acc.w = ((a[0].w + a[1].w) + (a[2].w + a[3].w)) + ((a[4].w + a[5].w) + (a[6].w + a[7].w));

    __shared__ float4 red[4][64];
    red[ng][dl] = acc;
    __syncthreads();
    if (threadIdx.x < 64) {
        float4 r0 = red[0][dl], r1 = red[1][dl], r2 = red[2][dl], r3 = red[3][dl];
        float* fp = &feat[b * DD + d0 + dl * 4];
        atomicAdd(&fp[0], (r0.x + r1.x) + (r2.x + r3.x));
        atomicAdd(&fp[1], (r0.y + r1.y) + (r2.y + r3.y));
        atomicAdd(&fp[2], (r0.z + r1.z) + (r2.z + r3.z));
        atomicAdd(&fp[3], (r0.w + r1.w) + (r2.w + r3.w));
    }
}

// ---------------- Kernel 3b: dense fallback ----------------
__global__ __launch_bounds__(256) void fapf_feat_dense(
    const float* __restrict__ x, const float* __restrict__ weights,
    float* __restrict__ feat)
{
    const int b  = blockIdx.y;
    const int d0 = blockIdx.x * 64;
    const int dl = threadIdx.x & 63;
    const int ng = threadIdx.x >> 6;   // 0..3

    const float* xb = x + (size_t)b * NN * DD;
    const float* wb = weights + b * NN;

    float a0 = 0.f, a1 = 0.f, a2 = 0.f, a3 = 0.f;
    for (int n = ng; n < NN; n += 16) {
        float w0 = wb[n], w1v = wb[n + 4], w2v = wb[n + 8], w3 = wb[n + 12];
        float v0 = xb[(size_t)(n)      * DD + d0 + dl];
        float v1 = xb[(size_t)(n + 4)  * DD + d0 + dl];
        float v2 = xb[(size_t)(n + 8)  * DD + d0 + dl];
        float v3 = xb[(size_t)(n + 12) * DD + d0 + dl];
        a0 = fmaf(w0, v0, a0);
        a1 = fmaf(w1v, v1, a1);
        a2 = fmaf(w2v, v2, a2);
        a3 = fmaf(w3, v3, a3);
    }
    float acc = (a0 + a1) + (a2 + a3);

    __shared__ float red[4][64];
    red[ng][dl] = acc;
    __syncthreads();
    if (threadIdx.x < 64) {
        feat[b * DD + d0 + dl] =
            (red[0][dl] + red[1][dl]) + (red[2][dl] + red[3][dl]);
    }
}

extern "C" void kernel_launch(void* const* d_in, const int* in_sizes, int n_in,
                              void* d_out, int out_size, void* d_ws, size_t ws_size,
                              hipStream_t stream) {
    const float* x   = (const float*)d_in[0];
    const float* w1  = (const float*)d_in[1];
    const float* b1  = (const float*)d_in[2];
    const float* w2  = (const float*)d_in[3];
    const float* b2  = (const float*)d_in[4];
    const int*   pct = (const int*)d_in[5];

    float* out = (float*)d_out;
    float* feat    = out;                         // [32,768]
    float* weights = out + BB * DD;               // [32,4096]
    float* scores  = weights + BB * NN;           // [32,4096]
    float* mask    = scores + BB * NN;            // [32,4096]

    // d_ws layout: whf (576KB) | wlf (576KB) | kidx (512KB) | kw (512KB) | kcnt (128B)
    short* whf  = (short*)d_ws;
    short* wlf  = whf + 24 * 24 * 64 * 8;
    int*   kidx = (int*)(wlf + 24 * 24 * 64 * 8);
    float* kw   = (float*)(kidx + BB * NN);
    int*   kcnt = (int*)(kw + BB * NN);

    const size_t needed = 2 * (size_t)(24 * 24 * 64 * 8) * sizeof(short)
                        + (size_t)BB * NN * (sizeof(int) + sizeof(float))
                        + BB * sizeof(int);
    const bool compact = ws_size >= needed;

    fapf_prep_w<<<dim3(24, 24), dim3(64), 0, stream>>>(w1, whf, wlf);
    fapf_scores_mfma<<<dim3(BB * NN / 32), dim3(256), 0, stream>>>(
        x, whf, wlf, b1, w2, b2, scores);
    fapf_select_kernel<<<dim3(BB), dim3(1024), 0, stream>>>(
        scores, pct, weights, mask, feat,
        compact ? kidx : (int*)nullptr, kw, kcnt);
    if (compact) {
        fapf_feat_compact<<<dim3(DD / 256, BB, NCH), dim3(256), 0, stream>>>(
            x, kidx, kw, kcnt, feat);
    } else {
        fapf_feat_dense<<<dim3(DD / 64, BB), dim3(256), 0, stream>>>(
            x, weights, feat);
    }
}